// Round 1
// baseline (18363.576 us; speedup 1.0000x reference)
//
#include <hip/hip_runtime.h>
#include <cstdint>

typedef __attribute__((ext_vector_type(8))) short short8;
typedef __attribute__((ext_vector_type(4))) float f32x4;
typedef __attribute__((ext_vector_type(4))) unsigned int u32x4;

#define B_ 128
#define L_ 256
#define E_ 512
#define H_ 512
#define TH_ 1536

#define PACK_PER_CS 24576                    // ushorts per (mat, cs): 16 ks * 3 f * 64 lanes * 8
#define PACK_TOTAL (8 * 32 * PACK_PER_CS)    // 6,291,456 ushorts
#define HPUB_OFF ((size_t)PACK_TOTAL * 2)    // 12,582,912 bytes
#define HPUB_USHORTS (2 * 2 * 128 * 512)     // 262,144 (2 buffers x 2 dirs x 128 x 512)
#define CNT_OFF (HPUB_OFF + (size_t)HPUB_USHORTS * 2)

__device__ __forceinline__ unsigned short f2bf(float v) {
    unsigned int u = __builtin_bit_cast(unsigned int, v);
    u += 0x7FFFu + ((u >> 16) & 1u);
    return (unsigned short)(u >> 16);
}
__device__ __forceinline__ float sigm_(float x) { return 1.f / (1.f + __expf(-x)); }
__device__ __forceinline__ float tanh_(float x) {
    float e = __expf(2.f * x);
    return 1.f - 2.f / (e + 1.f);
}

// Pack all 8 weight matrices ([512 x 1536] each) into per-(mat, colslice) MFMA
// fragment layout: elem idx = ((((mat*32+cs)*16 + ks)*3 + f)*64 + lane)*8 + e
// holds U[k][col] with k = ks*32 + (lane>>4)*8 + e, col = f*512 + cs*16 + (lane&15).
__global__ void pack_weights(const float* __restrict__ fWx, const float* __restrict__ fUh,
                             const float* __restrict__ ftU, const float* __restrict__ bWx,
                             const float* __restrict__ bUh, const float* __restrict__ btU,
                             unsigned short* __restrict__ pack) {
    unsigned int idx = blockIdx.x * 256u + threadIdx.x;
    if (idx >= (unsigned)PACK_TOTAL) return;
    int e = idx & 7;
    int l = (idx >> 3) & 63;
    unsigned int r = idx >> 9;
    int f = r % 3; r /= 3;
    int ks = r & 15; r >>= 4;
    int cs = r & 31; r >>= 5;
    int m = r;  // 0..7: {f_Wx, f_Uh, f_tU0, f_tU1, b_Wx, b_Uh, b_tU0, b_tU1}
    int k = ks * 32 + (l >> 4) * 8 + e;
    int col = f * 512 + cs * 16 + (l & 15);
    const float* src;
    switch (m) {
        case 0: src = fWx; break;
        case 1: src = fUh; break;
        case 2: src = ftU; break;
        case 3: src = ftU + H_ * TH_; break;
        case 4: src = bWx; break;
        case 5: src = bUh; break;
        case 6: src = btU; break;
        default: src = btU + H_ * TH_; break;
    }
    pack[idx] = f2bf(src[(size_t)k * TH_ + col]);
}

__device__ __forceinline__ void gbarrier(unsigned int* c, unsigned int tgt) {
    __threadfence();
    __syncthreads();
    if (threadIdx.x == 0) {
        __hip_atomic_fetch_add(c, 1u, __ATOMIC_RELEASE, __HIP_MEMORY_SCOPE_AGENT);
        while (__hip_atomic_load(c, __ATOMIC_ACQUIRE, __HIP_MEMORY_SCOPE_AGENT) < tgt) {
            __builtin_amdgcn_s_sleep(2);
        }
    }
    __syncthreads();
}

// One transition GRU cell (gx = bias only). Reads h (bf16) from hrd, weights from LDS pack,
// updates register h state and publishes bf16 h to hwr.
__device__ __forceinline__ void trans_cell(const unsigned short* hrd, const unsigned short* ldsp,
                                           int lane, float br, float bz, float bhh,
                                           const float* mm, float* hreg, unsigned short* hwr,
                                           int aoff, int rowC0, int hcol) {
    f32x4 acc0 = {0.f, 0.f, 0.f, 0.f}, acc1 = acc0, acc2 = acc0;
    const unsigned short* hp = hrd + aoff;
#pragma unroll
    for (int ks = 0; ks < 16; ++ks) {
        short8 A = *(const short8*)(hp + ks * 32);
        short8 B0 = *(const short8*)(ldsp + (ks * 3 + 0) * 512 + lane * 8);
        short8 B1 = *(const short8*)(ldsp + (ks * 3 + 1) * 512 + lane * 8);
        short8 B2 = *(const short8*)(ldsp + (ks * 3 + 2) * 512 + lane * 8);
        acc0 = __builtin_amdgcn_mfma_f32_16x16x32_bf16(A, B0, acc0, 0, 0, 0);
        acc1 = __builtin_amdgcn_mfma_f32_16x16x32_bf16(A, B1, acc1, 0, 0, 0);
        acc2 = __builtin_amdgcn_mfma_f32_16x16x32_bf16(A, B2, acc2, 0, 0, 0);
    }
#pragma unroll
    for (int j = 0; j < 4; ++j) {
        float r = sigm_(acc0[j] + br);
        float z = sigm_(acc1[j] + bz);
        float ht = tanh_(bhh + r * acc2[j]);
        float hn = (1.f - z) * ht + z * hreg[j];
        hn = mm[j] * hn + (1.f - mm[j]) * hreg[j];
        hreg[j] = hn;
        hwr[(rowC0 + j) * 512 + hcol] = f2bf(hn);
    }
}

__global__ __launch_bounds__(256, 1) void rnn_kernel(
    const float* __restrict__ xs, const float* __restrict__ xmask,
    const float* __restrict__ fb, const float* __restrict__ bb,
    const float* __restrict__ ftb, const float* __restrict__ btb,
    float* __restrict__ out, const unsigned short* __restrict__ pack,
    unsigned short* __restrict__ hpub, unsigned int* __restrict__ cnt) {
    extern __shared__ unsigned short lds_u16[];
    const int tid = threadIdx.x;
    const int wg = blockIdx.x;   // 0..127
    const int dir = wg >> 6;     // 0 fwd, 1 bwd
    const int bh = (wg >> 5) & 1;
    const int cs = wg & 31;      // column slice: h-cols [cs*16, cs*16+16)
    const int w = tid >> 6;      // wave 0..3 -> 16-row M block
    const int lane = tid & 63;

    // Load resident weight packs (Uh, tU0, tU1 slices) into LDS: 3 x 49152 B.
    for (int m = 0; m < 3; ++m) {
        const u32x4* src = (const u32x4*)(pack + (size_t)((dir * 4 + 1 + m) * 32 + cs) * PACK_PER_CS);
        u32x4* dst = (u32x4*)(lds_u16 + m * PACK_PER_CS);
        for (int i = tid; i < PACK_PER_CS / 8; i += 256) dst[i] = src[i];
    }
    __syncthreads();

    const int c16 = lane & 15;
    const int kg = lane >> 4;
    const int rowA = bh * 64 + w * 16 + c16;   // A-fragment row (global batch idx)
    const int rowC0 = bh * 64 + w * 16 + kg * 4;  // C rows base (global batch idx)
    const int hcol = cs * 16 + c16;

    const float* bsrc = dir ? bb : fb;
    const float* tbsrc = dir ? btb : ftb;
    const float b0r = bsrc[hcol], b0z = bsrc[512 + hcol], b0h = bsrc[1024 + hcol];
    const float b1r = tbsrc[hcol], b1z = tbsrc[512 + hcol], b1h = tbsrc[1024 + hcol];
    const float b2r = tbsrc[TH_ + hcol], b2z = tbsrc[TH_ + 512 + hcol], b2h = tbsrc[TH_ + 1024 + hcol];

    float hreg[4] = {0.f, 0.f, 0.f, 0.f};

    unsigned int* grpcnt = cnt + (dir * 2 + bh);
    unsigned int tgt = 0;

    const unsigned short* wxpack =
        pack + (size_t)((dir * 4 + 0) * 32 + cs) * PACK_PER_CS + lane * 8;
    unsigned short* hp0 = hpub + (0 * 2 + dir) * 128 * 512;
    unsigned short* hp1 = hpub + (1 * 2 + dir) * 128 * 512;
    const int ka = kg * 8;
    const int aoff = rowA * 512 + ka;
    const float* xrow = xs + (size_t)rowA * L_ * E_ + ka;

    int pc = 0;  // buffer currently holding the h to be read
    for (int s = 0; s < L_; ++s) {
        const int t = dir ? (L_ - 1 - s) : s;
        float mm[4];
#pragma unroll
        for (int j = 0; j < 4; ++j) mm[j] = xmask[(rowC0 + j) * L_ + t];

        // ---------------- CELL 0 (LGRU: gx = x@Wx + b) ----------------
        {
            f32x4 acc0 = {0.f, 0.f, 0.f, 0.f}, acc1 = acc0, accgh = acc0, accgx = acc0;
            const unsigned short* hrd = (pc ? hp1 : hp0) + aoff;
            const float* xp = xrow + (size_t)t * E_;
#pragma unroll
            for (int ks = 0; ks < 16; ++ks) {
                short8 A1 = *(const short8*)(hrd + ks * 32);
                f32x4 x0 = *(const f32x4*)(xp + ks * 32);
                f32x4 x1 = *(const f32x4*)(xp + ks * 32 + 4);
                short8 A2;
#pragma unroll
                for (int e = 0; e < 4; ++e) {
                    A2[e] = (short)f2bf(x0[e]);
                    A2[4 + e] = (short)f2bf(x1[e]);
                }
                short8 B0 = *(const short8*)(lds_u16 + (ks * 3 + 0) * 512 + lane * 8);
                short8 B1 = *(const short8*)(lds_u16 + (ks * 3 + 1) * 512 + lane * 8);
                short8 B2 = *(const short8*)(lds_u16 + (ks * 3 + 2) * 512 + lane * 8);
                short8 W0 = *(const short8*)(wxpack + (ks * 3 + 0) * 512);
                short8 W1 = *(const short8*)(wxpack + (ks * 3 + 1) * 512);
                short8 W2 = *(const short8*)(wxpack + (ks * 3 + 2) * 512);
                acc0 = __builtin_amdgcn_mfma_f32_16x16x32_bf16(A1, B0, acc0, 0, 0, 0);
                acc1 = __builtin_amdgcn_mfma_f32_16x16x32_bf16(A1, B1, acc1, 0, 0, 0);
                accgh = __builtin_amdgcn_mfma_f32_16x16x32_bf16(A1, B2, accgh, 0, 0, 0);
                acc0 = __builtin_amdgcn_mfma_f32_16x16x32_bf16(A2, W0, acc0, 0, 0, 0);
                acc1 = __builtin_amdgcn_mfma_f32_16x16x32_bf16(A2, W1, acc1, 0, 0, 0);
                accgx = __builtin_amdgcn_mfma_f32_16x16x32_bf16(A2, W2, accgx, 0, 0, 0);
            }
            unsigned short* hwr = pc ? hp0 : hp1;
#pragma unroll
            for (int j = 0; j < 4; ++j) {
                float r = sigm_(acc0[j] + b0r);
                float z = sigm_(acc1[j] + b0z);
                float ht = tanh_(accgx[j] + b0h + r * accgh[j]);
                float hn = (1.f - z) * ht + z * hreg[j];
                hn = mm[j] * hn + (1.f - mm[j]) * hreg[j];
                hreg[j] = hn;
                hwr[(rowC0 + j) * 512 + hcol] = f2bf(hn);
            }
            pc ^= 1;
            tgt += 32;
            gbarrier(grpcnt, tgt);
        }
        // ---------------- CELL 1 (TGRU 0) ----------------
        {
            const unsigned short* hrd = pc ? hp1 : hp0;
            unsigned short* hwr = pc ? hp0 : hp1;
            trans_cell(hrd, lds_u16 + PACK_PER_CS, lane, b1r, b1z, b1h, mm, hreg, hwr, aoff,
                       rowC0, hcol);
            pc ^= 1;
            tgt += 32;
            gbarrier(grpcnt, tgt);
        }
        // ---------------- CELL 2 (TGRU 1) + output ----------------
        {
            const unsigned short* hrd = pc ? hp1 : hp0;
            unsigned short* hwr = pc ? hp0 : hp1;
            trans_cell(hrd, lds_u16 + 2 * PACK_PER_CS, lane, b2r, b2z, b2h, mm, hreg, hwr, aoff,
                       rowC0, hcol);
#pragma unroll
            for (int j = 0; j < 4; ++j) {
                out[(size_t)((rowC0 + j) * L_ + t) * 1024 + dir * 512 + hcol] = mm[j] * hreg[j];
            }
            pc ^= 1;
            tgt += 32;
            gbarrier(grpcnt, tgt);
        }
    }
}

extern "C" void kernel_launch(void* const* d_in, const int* in_sizes, int n_in, void* d_out,
                              int out_size, void* d_ws, size_t ws_size, hipStream_t stream) {
    (void)in_sizes; (void)n_in; (void)out_size; (void)ws_size;
    const float* xs = (const float*)d_in[0];
    const float* xmask = (const float*)d_in[1];
    const float* fWx = (const float*)d_in[2];
    const float* fUh = (const float*)d_in[3];
    const float* fb = (const float*)d_in[4];
    const float* bWx = (const float*)d_in[5];
    const float* bUh = (const float*)d_in[6];
    const float* bb = (const float*)d_in[7];
    const float* ftU = (const float*)d_in[8];
    const float* ftb = (const float*)d_in[9];
    const float* btU = (const float*)d_in[10];
    const float* btb = (const float*)d_in[11];

    unsigned short* pack = (unsigned short*)d_ws;
    unsigned short* hpub = (unsigned short*)((char*)d_ws + HPUB_OFF);
    unsigned int* cnt = (unsigned int*)((char*)d_ws + CNT_OFF);

    // zero h0 buffers + barrier counters
    hipMemsetAsync((char*)d_ws + HPUB_OFF, 0, (size_t)HPUB_USHORTS * 2 + 256, stream);

    pack_weights<<<PACK_TOTAL / 256, 256, 0, stream>>>(fWx, fUh, ftU, bWx, bUh, btU, pack);

    static int attr_set = 0;
    hipFuncSetAttribute((const void*)rnn_kernel, hipFuncAttributeMaxDynamicSharedMemorySize,
                        3 * PACK_PER_CS * 2);
    (void)attr_set;

    rnn_kernel<<<128, 256, 3 * PACK_PER_CS * 2, stream>>>(xs, xmask, fb, bb, ftb, btb,
                                                          (float*)d_out, pack, hpub, cnt);
}

// Round 2
// 4716.140 us; speedup vs baseline: 3.8938x; 3.8938x over previous
//
#include <hip/hip_runtime.h>
#include <cstdint>

typedef __attribute__((ext_vector_type(8))) short short8;
typedef __attribute__((ext_vector_type(4))) float f32x4;
typedef __attribute__((ext_vector_type(4))) unsigned int u32x4;

#define B_ 128
#define L_ 256
#define E_ 512
#define H_ 512
#define TH_ 1536

#define PACK_PER_CS 24576                    // ushorts per (mat, cs): 16 ks * 3 f * 64 lanes * 8
#define PACK_TOTAL (8 * 32 * PACK_PER_CS)    // 6,291,456 ushorts
#define HPUB_OFF ((size_t)PACK_TOTAL * 2)    // bytes
#define HPUB_USHORTS (2 * 2 * 128 * 512)     // 2 buffers x 2 dirs x 128 x 512
#define FLAG_OFF (HPUB_OFF + (size_t)HPUB_USHORTS * 2)
#define FLAG_BYTES 512                       // 4 groups x 32 uints

__device__ __forceinline__ unsigned short f2bf(float v) {
    unsigned int u = __builtin_bit_cast(unsigned int, v);
    u += 0x7FFFu + ((u >> 16) & 1u);
    return (unsigned short)(u >> 16);
}
__device__ __forceinline__ float sigm_(float x) { return 1.f / (1.f + __expf(-x)); }
__device__ __forceinline__ float tanh_(float x) {
    float e = __expf(2.f * x);
    return 1.f - 2.f / (e + 1.f);
}

// Pack all 8 weight matrices ([512 x 1536] each) into per-(mat, colslice) MFMA
// fragment layout: elem idx = ((((mat*32+cs)*16 + ks)*3 + f)*64 + lane)*8 + e
// holds U[k][col] with k = ks*32 + (lane>>4)*8 + e, col = f*512 + cs*16 + (lane&15).
__global__ void pack_weights(const float* __restrict__ fWx, const float* __restrict__ fUh,
                             const float* __restrict__ ftU, const float* __restrict__ bWx,
                             const float* __restrict__ bUh, const float* __restrict__ btU,
                             unsigned short* __restrict__ pack) {
    unsigned int idx = blockIdx.x * 256u + threadIdx.x;
    if (idx >= (unsigned)PACK_TOTAL) return;
    int e = idx & 7;
    int l = (idx >> 3) & 63;
    unsigned int r = idx >> 9;
    int f = r % 3; r /= 3;
    int ks = r & 15; r >>= 4;
    int cs = r & 31; r >>= 5;
    int m = r;  // 0..7: {f_Wx, f_Uh, f_tU0, f_tU1, b_Wx, b_Uh, b_tU0, b_tU1}
    int k = ks * 32 + (l >> 4) * 8 + e;
    int col = f * 512 + cs * 16 + (l & 15);
    const float* src;
    switch (m) {
        case 0: src = fWx; break;
        case 1: src = fUh; break;
        case 2: src = ftU; break;
        case 3: src = ftU + H_ * TH_; break;
        case 4: src = bWx; break;
        case 5: src = bUh; break;
        case 6: src = btU; break;
        default: src = btU + H_ * TH_; break;
    }
    pack[idx] = f2bf(src[(size_t)k * TH_ + col]);
}

// ---- cross-WG sync primitives: no L2 maintenance anywhere ----
// h publishes are write-through (sc0 sc1) -> coherence point; __syncthreads drains vmcnt;
// leader then relaxed-stores a monotonic cell count to its own flag (sc1, no wbl2).
__device__ __forceinline__ void g_arrive(unsigned int* myflag, unsigned int val, int tid) {
    __syncthreads();
    if (tid == 0)
        __hip_atomic_store(myflag, val, __ATOMIC_RELAXED, __HIP_MEMORY_SCOPE_AGENT);
}
// Waiters poll all 32 group flags with relaxed loads (no buffer_inv). h reads bypass
// caches (sc0 sc1), so no acquire fence is needed and weights/xs stay L2-hot.
__device__ __forceinline__ void g_wait(const unsigned int* gflags, unsigned int need, int tid) {
    if (tid < 64) {
        const unsigned int* f = gflags + (tid & 31);
        while (true) {
            unsigned int v = __hip_atomic_load(f, __ATOMIC_RELAXED, __HIP_MEMORY_SCOPE_AGENT);
            if (__all((int)(v >= need))) break;
            __builtin_amdgcn_s_sleep(1);
        }
    }
    __syncthreads();
    __builtin_amdgcn_sched_barrier(0);
}

__device__ __forceinline__ void st_h(unsigned short* p, unsigned int v) {
    asm volatile("global_store_short %0, %1, off sc0 sc1" :: "v"(p), "v"(v) : "memory");
}

// One transition GRU cell (gx = bias only). h read via sc0sc1 bypass loads.
__device__ __forceinline__ void trans_cell(const unsigned short* hp, const unsigned short* ldsp,
                                           int lane, float br, float bz, float bhh,
                                           const float* mm, float* hreg, unsigned short* hwr,
                                           int rowC0, int hcol) {
    short8 A[16];
#pragma unroll
    for (int ks = 0; ks < 16; ++ks)
        asm volatile("global_load_dwordx4 %0, %1, off sc0 sc1"
                     : "=v"(A[ks]) : "v"(hp + ks * 32) : "memory");
    f32x4 acc0 = {0.f, 0.f, 0.f, 0.f}, acc1 = acc0, acc2 = acc0;
    asm volatile("s_waitcnt vmcnt(8)" ::: "memory");
    __builtin_amdgcn_sched_barrier(0);
#pragma unroll
    for (int ks = 0; ks < 8; ++ks) {
        short8 B0 = *(const short8*)(ldsp + (ks * 3 + 0) * 512 + lane * 8);
        short8 B1 = *(const short8*)(ldsp + (ks * 3 + 1) * 512 + lane * 8);
        short8 B2 = *(const short8*)(ldsp + (ks * 3 + 2) * 512 + lane * 8);
        acc0 = __builtin_amdgcn_mfma_f32_16x16x32_bf16(A[ks], B0, acc0, 0, 0, 0);
        acc1 = __builtin_amdgcn_mfma_f32_16x16x32_bf16(A[ks], B1, acc1, 0, 0, 0);
        acc2 = __builtin_amdgcn_mfma_f32_16x16x32_bf16(A[ks], B2, acc2, 0, 0, 0);
    }
    asm volatile("s_waitcnt vmcnt(0)" ::: "memory");
    __builtin_amdgcn_sched_barrier(0);
#pragma unroll
    for (int ks = 8; ks < 16; ++ks) {
        short8 B0 = *(const short8*)(ldsp + (ks * 3 + 0) * 512 + lane * 8);
        short8 B1 = *(const short8*)(ldsp + (ks * 3 + 1) * 512 + lane * 8);
        short8 B2 = *(const short8*)(ldsp + (ks * 3 + 2) * 512 + lane * 8);
        acc0 = __builtin_amdgcn_mfma_f32_16x16x32_bf16(A[ks], B0, acc0, 0, 0, 0);
        acc1 = __builtin_amdgcn_mfma_f32_16x16x32_bf16(A[ks], B1, acc1, 0, 0, 0);
        acc2 = __builtin_amdgcn_mfma_f32_16x16x32_bf16(A[ks], B2, acc2, 0, 0, 0);
    }
#pragma unroll
    for (int j = 0; j < 4; ++j) {
        float r = sigm_(acc0[j] + br);
        float z = sigm_(acc1[j] + bz);
        float ht = tanh_(bhh + r * acc2[j]);
        float hn = (1.f - z) * ht + z * hreg[j];
        hn = mm[j] * hn + (1.f - mm[j]) * hreg[j];
        hreg[j] = hn;
        st_h(hwr + (rowC0 + j) * 512 + hcol, (unsigned int)f2bf(hn));
    }
}

__global__ __launch_bounds__(256, 1) void rnn_kernel(
    const float* __restrict__ xs, const float* __restrict__ xmask,
    const float* __restrict__ fb, const float* __restrict__ bb,
    const float* __restrict__ ftb, const float* __restrict__ btb,
    float* __restrict__ out, const unsigned short* __restrict__ pack,
    unsigned short* __restrict__ hpub, unsigned int* __restrict__ flags) {
    extern __shared__ unsigned short lds_u16[];
    const int tid = threadIdx.x;
    const int wg = blockIdx.x;   // 0..127
    const int dir = wg >> 6;     // 0 fwd, 1 bwd
    const int bh = (wg >> 5) & 1;
    const int cs = wg & 31;      // column slice: h-cols [cs*16, cs*16+16)
    const int w = tid >> 6;      // wave 0..3 -> 16-row M block
    const int lane = tid & 63;

    // Load resident weight packs (Uh, tU0, tU1 slices) into LDS: 3 x 49152 B.
    for (int m = 0; m < 3; ++m) {
        const u32x4* src = (const u32x4*)(pack + (size_t)((dir * 4 + 1 + m) * 32 + cs) * PACK_PER_CS);
        u32x4* dst = (u32x4*)(lds_u16 + m * PACK_PER_CS);
        for (int i = tid; i < PACK_PER_CS / 8; i += 256) dst[i] = src[i];
    }
    __syncthreads();

    const int c16 = lane & 15;
    const int kg = lane >> 4;
    const int rowA = bh * 64 + w * 16 + c16;      // A-fragment row (global batch idx)
    const int rowC0 = bh * 64 + w * 16 + kg * 4;  // C rows base
    const int hcol = cs * 16 + c16;

    const float* bsrc = dir ? bb : fb;
    const float* tbsrc = dir ? btb : ftb;
    const float b0r = bsrc[hcol], b0z = bsrc[512 + hcol], b0h = bsrc[1024 + hcol];
    const float b1r = tbsrc[hcol], b1z = tbsrc[512 + hcol], b1h = tbsrc[1024 + hcol];
    const float b2r = tbsrc[TH_ + hcol], b2z = tbsrc[TH_ + 512 + hcol], b2h = tbsrc[TH_ + 1024 + hcol];

    float hreg[4] = {0.f, 0.f, 0.f, 0.f};

    unsigned int* gflags = flags + (dir * 2 + bh) * 32;
    unsigned int* myflag = gflags + cs;
    unsigned int need = 0;

    const unsigned short* wxpack =
        pack + (size_t)((dir * 4 + 0) * 32 + cs) * PACK_PER_CS + lane * 8;
    unsigned short* hp0 = hpub + (0 * 2 + dir) * 128 * 512;
    unsigned short* hp1 = hpub + (1 * 2 + dir) * 128 * 512;
    const int ka = kg * 8;
    const int aoff = rowA * 512 + ka;
    const float* xrow = xs + (size_t)rowA * L_ * E_ + ka;

    int pc = 0;  // buffer currently holding the h to be read
    for (int s = 0; s < L_; ++s) {
        const int t = dir ? (L_ - 1 - s) : s;
        float mm[4];
#pragma unroll
        for (int j = 0; j < 4; ++j) mm[j] = xmask[(rowC0 + j) * L_ + t];

        // ---- CELL 0 x-part (h-independent): runs while prev barrier settles ----
        f32x4 acc0 = {0.f, 0.f, 0.f, 0.f}, acc1 = acc0, accgx = acc0;
        {
            const float* xp = xrow + (size_t)t * E_;
#pragma unroll
            for (int ks = 0; ks < 16; ++ks) {
                f32x4 x0 = *(const f32x4*)(xp + ks * 32);
                f32x4 x1 = *(const f32x4*)(xp + ks * 32 + 4);
                short8 A2;
#pragma unroll
                for (int e = 0; e < 4; ++e) {
                    A2[e] = (short)f2bf(x0[e]);
                    A2[4 + e] = (short)f2bf(x1[e]);
                }
                short8 W0 = *(const short8*)(wxpack + (ks * 3 + 0) * 512);
                short8 W1 = *(const short8*)(wxpack + (ks * 3 + 1) * 512);
                short8 W2 = *(const short8*)(wxpack + (ks * 3 + 2) * 512);
                acc0 = __builtin_amdgcn_mfma_f32_16x16x32_bf16(A2, W0, acc0, 0, 0, 0);
                acc1 = __builtin_amdgcn_mfma_f32_16x16x32_bf16(A2, W1, acc1, 0, 0, 0);
                accgx = __builtin_amdgcn_mfma_f32_16x16x32_bf16(A2, W2, accgx, 0, 0, 0);
            }
        }
        g_wait(gflags, need, tid);
        // ---- CELL 0 h-part ----
        {
            const unsigned short* hp = (pc ? hp1 : hp0) + aoff;
            short8 A[16];
#pragma unroll
            for (int ks = 0; ks < 16; ++ks)
                asm volatile("global_load_dwordx4 %0, %1, off sc0 sc1"
                             : "=v"(A[ks]) : "v"(hp + ks * 32) : "memory");
            f32x4 accgh = {0.f, 0.f, 0.f, 0.f};
            asm volatile("s_waitcnt vmcnt(8)" ::: "memory");
            __builtin_amdgcn_sched_barrier(0);
#pragma unroll
            for (int ks = 0; ks < 8; ++ks) {
                short8 B0 = *(const short8*)(lds_u16 + (ks * 3 + 0) * 512 + lane * 8);
                short8 B1 = *(const short8*)(lds_u16 + (ks * 3 + 1) * 512 + lane * 8);
                short8 B2 = *(const short8*)(lds_u16 + (ks * 3 + 2) * 512 + lane * 8);
                acc0 = __builtin_amdgcn_mfma_f32_16x16x32_bf16(A[ks], B0, acc0, 0, 0, 0);
                acc1 = __builtin_amdgcn_mfma_f32_16x16x32_bf16(A[ks], B1, acc1, 0, 0, 0);
                accgh = __builtin_amdgcn_mfma_f32_16x16x32_bf16(A[ks], B2, accgh, 0, 0, 0);
            }
            asm volatile("s_waitcnt vmcnt(0)" ::: "memory");
            __builtin_amdgcn_sched_barrier(0);
#pragma unroll
            for (int ks = 8; ks < 16; ++ks) {
                short8 B0 = *(const short8*)(lds_u16 + (ks * 3 + 0) * 512 + lane * 8);
                short8 B1 = *(const short8*)(lds_u16 + (ks * 3 + 1) * 512 + lane * 8);
                short8 B2 = *(const short8*)(lds_u16 + (ks * 3 + 2) * 512 + lane * 8);
                acc0 = __builtin_amdgcn_mfma_f32_16x16x32_bf16(A[ks], B0, acc0, 0, 0, 0);
                acc1 = __builtin_amdgcn_mfma_f32_16x16x32_bf16(A[ks], B1, acc1, 0, 0, 0);
                accgh = __builtin_amdgcn_mfma_f32_16x16x32_bf16(A[ks], B2, accgh, 0, 0, 0);
            }
            unsigned short* hwr = pc ? hp0 : hp1;
#pragma unroll
            for (int j = 0; j < 4; ++j) {
                float r = sigm_(acc0[j] + b0r);
                float z = sigm_(acc1[j] + b0z);
                float ht = tanh_(accgx[j] + b0h + r * accgh[j]);
                float hn = (1.f - z) * ht + z * hreg[j];
                hn = mm[j] * hn + (1.f - mm[j]) * hreg[j];
                hreg[j] = hn;
                st_h(hwr + (rowC0 + j) * 512 + hcol, (unsigned int)f2bf(hn));
            }
            pc ^= 1;
        }
        need++;
        g_arrive(myflag, need, tid);
        // ---- CELL 1 (TGRU 0) ----
        g_wait(gflags, need, tid);
        trans_cell((pc ? hp1 : hp0) + aoff, lds_u16 + PACK_PER_CS, lane, b1r, b1z, b1h, mm,
                   hreg, pc ? hp0 : hp1, rowC0, hcol);
        pc ^= 1;
        need++;
        g_arrive(myflag, need, tid);
        // ---- CELL 2 (TGRU 1) + output ----
        g_wait(gflags, need, tid);
        trans_cell((pc ? hp1 : hp0) + aoff, lds_u16 + 2 * PACK_PER_CS, lane, b2r, b2z, b2h, mm,
                   hreg, pc ? hp0 : hp1, rowC0, hcol);
        pc ^= 1;
        need++;
        g_arrive(myflag, need, tid);
#pragma unroll
        for (int j = 0; j < 4; ++j) {
            out[(size_t)((rowC0 + j) * L_ + t) * 1024 + dir * 512 + hcol] = mm[j] * hreg[j];
        }
    }
}

extern "C" void kernel_launch(void* const* d_in, const int* in_sizes, int n_in, void* d_out,
                              int out_size, void* d_ws, size_t ws_size, hipStream_t stream) {
    (void)in_sizes; (void)n_in; (void)out_size; (void)ws_size;
    const float* xs = (const float*)d_in[0];
    const float* xmask = (const float*)d_in[1];
    const float* fWx = (const float*)d_in[2];
    const float* fUh = (const float*)d_in[3];
    const float* fb = (const float*)d_in[4];
    const float* bWx = (const float*)d_in[5];
    const float* bUh = (const float*)d_in[6];
    const float* bb = (const float*)d_in[7];
    const float* ftU = (const float*)d_in[8];
    const float* ftb = (const float*)d_in[9];
    const float* btU = (const float*)d_in[10];
    const float* btb = (const float*)d_in[11];

    unsigned short* pack = (unsigned short*)d_ws;
    unsigned short* hpub = (unsigned short*)((char*)d_ws + HPUB_OFF);
    unsigned int* flags = (unsigned int*)((char*)d_ws + FLAG_OFF);

    // zero h0 buffers + flags (also resets state for every graph replay)
    hipMemsetAsync((char*)d_ws + HPUB_OFF, 0, (size_t)HPUB_USHORTS * 2 + FLAG_BYTES, stream);

    pack_weights<<<PACK_TOTAL / 256, 256, 0, stream>>>(fWx, fUh, ftU, bWx, bUh, btU, pack);

    hipFuncSetAttribute((const void*)rnn_kernel, hipFuncAttributeMaxDynamicSharedMemorySize,
                        3 * PACK_PER_CS * 2);

    rnn_kernel<<<128, 256, 3 * PACK_PER_CS * 2, stream>>>(xs, xmask, fb, bb, ftb, btb,
                                                          (float*)d_out, pack, hpub, flags);
}